// Round 13
// baseline (404.886 us; speedup 1.0000x reference)
//
#include <hip/hip_runtime.h>
#include <math.h>

// Deformable-DETR encoder, 2 layers. Round 25: counted-vmcnt double-buffer
// in the HEALTHY mgemm shapes. R24 landed (418.8 -> 394.7). R20 showed
// FFN1 traffic-bound at only 2.18 TB/s: the single-buffered
// stage->syncthreads(vmcnt0 drain)->compute loop caps per-block BW at
// ~35% of achievable even at 6 blocks/CU. T4 (counted vmcnt) was only
// ever tried on the starved mgemm_ln (R15: null, nothing to overlap);
// now applied where overlap exists: dbuf LDS (TM=64: 48 KB, 3 blocks/CU;
// TM=128: 64 KB, 2 blocks/CU), stage(t+2) after compute, wait vmcnt(6/8)
// so the prefetch crosses the barrier. All other R24 structure retained
// (XCD swizzle, fused-residual bf16 SUM epilogue, streaming LN).

#define S_TOT 13294
#define BATCH 2
#define M_TOT (BATCH * S_TOT)     // 26588
#define M_PAD 26624               // 208*128 = 416*64

typedef __attribute__((ext_vector_type(8))) short short8;
typedef __attribute__((ext_vector_type(4))) float floatx4;
typedef __attribute__((ext_vector_type(2))) float floatx2;

#define AS1C(p) ((const __attribute__((address_space(1))) void*)(p))
#define AS3(p)  ((__attribute__((address_space(3))) void*)(p))

static __device__ __forceinline__ unsigned short f2bf(float x) {
    union { float f; unsigned u; } v; v.f = x;
    unsigned r = v.u + 0x7FFFu + ((v.u >> 16) & 1u);
    return (unsigned short)(r >> 16);
}
static __device__ __forceinline__ float b2f(unsigned short u) {
    union { unsigned u; float f; } v; v.u = (unsigned)u << 16; return v.f;
}
static __device__ __forceinline__ float bflo(unsigned u) {
    union { unsigned u; float f; } v; v.u = u << 16; return v.f;
}
static __device__ __forceinline__ float bfhi(unsigned u) {
    union { unsigned u; float f; } v; v.u = u & 0xFFFF0000u; return v.f;
}
// hi bf16 with low-half mantissa garbage (<=2^-7 rel, below bf16 rounding
// scale for our magnitudes) — saves the AND.
static __device__ __forceinline__ float braw(unsigned u) {
    union { unsigned u; float f; } v; v.u = u; return v.f;
}

// ---------------------------------------------------------------------------
// bf16 MFMA GEMM, BK=64, DOUBLE-BUFFERED with counted vmcnt (T4).
// 1-D grid, XCD-swizzled decode (id&7 = XCD owns contiguous bm range).
// Per-wave loads per stage: TM=64 -> 6, TM=128 -> 8; wait vmcnt(N) keeps
// the newer stage's loads in flight across the barrier.
// TM=128: 4 waves 2x2 of 64x64. TM=64: 4 waves 64x32.
// PROJ: col<256 -> bf16 Cb[.,256]; col>=256 -> bf16 Cb2[.,384].
// SUM:  bf16 out = acc + bias + residual R (pre-LN sum, single [M,256]).
// ---------------------------------------------------------------------------
template<int TM, bool RELU, bool BF16OUT, bool PROJ, bool SUM>
__global__ __launch_bounds__(256)
void mgemm(const unsigned short* __restrict__ A,
           const unsigned short* __restrict__ BT,
           const float* __restrict__ bias,
           const float* __restrict__ bias2,
           const float* __restrict__ bias3,
           const unsigned short* __restrict__ R,   // bf16 residual [M_PAD,256]
           unsigned short* __restrict__ Cb,
           unsigned short* __restrict__ Cb2,
           int nbmPer,          // (M_PAD/TM)/8
           int M, int N, int K)
{
    constexpr int WM = (TM == 128) ? 2 : 1;
    constexpr int WN = 4 / WM;
    constexpr int MI = TM / (WM * 16);
    constexpr int NI = 128 / (WN * 16);
    constexpr int ABUF = TM * 64;        // shorts per A buffer
    __shared__ __align__(16) unsigned short smemA[2 * ABUF];
    __shared__ __align__(16) unsigned short smemB[2 * 8192];
    const int tid  = threadIdx.x;
    const int lane = tid & 63;
    const int w    = tid >> 6;
    const int wm   = w % WM, wn = w / WM;
    const int lr   = lane & 15, quad = lane >> 4;
    // XCD swizzle: consecutive ids round-robin XCDs; give XCD x a
    // contiguous bm chunk across all bn.
    const int id  = blockIdx.x;
    const int x8  = id & 7;
    const int k9  = id >> 3;
    const int bm  = (x8 * nbmPer + (k9 % nbmPer)) * TM;
    const int bn  = (k9 / nbmPer) * 128;

    floatx4 acc[MI][NI];
    #pragma unroll
    for (int i = 0; i < MI; ++i)
        #pragma unroll
        for (int j = 0; j < NI; ++j)
            acc[i][j] = (floatx4){0.f, 0.f, 0.f, 0.f};

    const int srow = lane >> 2;
    const int selt = (lane & 3) << 3;

    // One stage = one 64-wide K-tile into buffer `buf`.
    auto stage = [&](int kt, int buf) {
        const int k0 = kt << 6;
        #pragma unroll
        for (int c = 0; c < 2; ++c) {
            if (TM == 128) {
                #pragma unroll
                for (int jj = 0; jj < 2; ++jj) {
                    const int j = 2 * w + jj;
                    const unsigned short* ga = A  + (size_t)(bm + j * 16 + srow) * K + k0 + c * 32 + selt;
                    const unsigned short* gb = BT + (size_t)(bn + j * 16 + srow) * K + k0 + c * 32 + selt;
                    __builtin_amdgcn_global_load_lds(AS1C(ga), AS3(smemA + buf * ABUF + c * (TM * 32) + j * 512), 16, 0, 0);
                    __builtin_amdgcn_global_load_lds(AS1C(gb), AS3(smemB + buf * 8192 + c * 4096 + j * 512), 16, 0, 0);
                }
            } else {
                const unsigned short* ga = A + (size_t)(bm + w * 16 + srow) * K + k0 + c * 32 + selt;
                __builtin_amdgcn_global_load_lds(AS1C(ga), AS3(smemA + buf * ABUF + c * (TM * 32) + w * 512), 16, 0, 0);
                #pragma unroll
                for (int jj = 0; jj < 2; ++jj) {
                    const int j = 2 * w + jj;
                    const unsigned short* gb = BT + (size_t)(bn + j * 16 + srow) * K + k0 + c * 32 + selt;
                    __builtin_amdgcn_global_load_lds(AS1C(gb), AS3(smemB + buf * 8192 + c * 4096 + j * 512), 16, 0, 0);
                }
            }
        }
    };

    const int NK = K >> 6;      // 4 or 16 for all our shapes
    stage(0, 0);
    stage(1, 1);
    for (int kt = 0; kt < NK; ++kt) {
        const int buf = kt & 1;
        // Counted wait: this buffer's loads are the oldest outstanding;
        // the newer stage's 6/8 loads stay in flight across the barrier.
        if (kt + 1 < NK) {
            if (TM == 128) asm volatile("s_waitcnt vmcnt(8)" ::: "memory");
            else           asm volatile("s_waitcnt vmcnt(6)" ::: "memory");
        } else {
            asm volatile("s_waitcnt vmcnt(0)" ::: "memory");
        }
        __builtin_amdgcn_s_barrier();

        #pragma unroll
        for (int c = 0; c < 2; ++c) {
            short8 av[MI], bv[NI];
            #pragma unroll
            for (int mi = 0; mi < MI; ++mi)
                av[mi] = *(const short8*)&smemA[buf * ABUF + c * (TM * 32) + (wm * MI * 16 + mi * 16 + lr) * 32 + quad * 8];
            #pragma unroll
            for (int ni = 0; ni < NI; ++ni)
                bv[ni] = *(const short8*)&smemB[buf * 8192 + c * 4096 + (wn * NI * 16 + ni * 16 + lr) * 32 + quad * 8];
            #pragma unroll
            for (int mi = 0; mi < MI; ++mi)
                #pragma unroll
                for (int ni = 0; ni < NI; ++ni)
                    acc[mi][ni] = __builtin_amdgcn_mfma_f32_16x16x32_bf16(
                        av[mi], bv[ni], acc[mi][ni], 0, 0, 0);
        }
        // All my LDS reads complete before anyone overwrites this buffer.
        asm volatile("s_waitcnt lgkmcnt(0)" ::: "memory");
        __builtin_amdgcn_s_barrier();
        if (kt + 2 < NK) stage(kt + 2, buf);    // refill freed buffer
    }

    #pragma unroll
    for (int mi = 0; mi < MI; ++mi) {
        #pragma unroll
        for (int ni = 0; ni < NI; ++ni) {
            #pragma unroll
            for (int r = 0; r < 4; ++r) {
                const int row = bm + wm * MI * 16 + mi * 16 + quad * 4 + r;
                const int col = bn + wn * NI * 16 + ni * 16 + lr;
                if (PROJ) {
                    const float bb = (col < 256) ? bias[col]
                                   : (col < 512) ? bias2[col - 256]
                                                 : bias3[col - 512];
                    const float v = acc[mi][ni][r] + bb;
                    if (col < 256) Cb[(size_t)row * 256 + col] = f2bf(v);
                    else           Cb2[(size_t)row * 384 + (col - 256)] = f2bf(v);
                } else if (SUM) {
                    const float v = acc[mi][ni][r] + bias[col]
                                  + b2f(R[(size_t)row * 256 + col]);
                    Cb[(size_t)row * 256 + col] = f2bf(v);
                } else {
                    float v = acc[mi][ni][r] + bias[col];
                    if (RELU) v = fmaxf(v, 0.0f);
                    if (BF16OUT) Cb[(size_t)row * N + col] = f2bf(v);
                }
            }
        }
    }
}

// ---------------------------------------------------------------------------
// Streaming LayerNorm over the pre-computed bf16 sum S [M,256] (residual
// already folded in by the GEMM epilogue). One 64-lane wave per row
// (4 bf16 per lane). Pure bandwidth kernel, 6647 blocks.
// ---------------------------------------------------------------------------
template<bool HASF, bool HASB>
__global__ __launch_bounds__(256)
void ln_kernel(const unsigned short* __restrict__ S,
               const float* __restrict__ g, const float* __restrict__ beta,
               float* __restrict__ outF, unsigned short* __restrict__ outB,
               int M)
{
    const int lane = threadIdx.x & 63;
    const int row  = blockIdx.x * 4 + (threadIdx.x >> 6);
    if (row >= M) return;
    const int c4 = lane * 4;
    const uint2 sv = *(const uint2*)(S + (size_t)row * 256 + c4);
    const float x0 = bflo(sv.x);
    const float x1 = bfhi(sv.x);
    const float x2 = bflo(sv.y);
    const float x3 = bfhi(sv.y);
    float p = (x0 + x1) + (x2 + x3);
    float q = (x0 * x0 + x1 * x1) + (x2 * x2 + x3 * x3);
    #pragma unroll
    for (int o = 1; o < 64; o <<= 1) {
        p += __shfl_xor(p, o, 64);
        q += __shfl_xor(q, o, 64);
    }
    const float mean = p * (1.0f / 256.0f);
    const float var  = q * (1.0f / 256.0f) - mean * mean;
    const float rs   = rsqrtf(var + 1e-5f);
    const float4 gv = *(const float4*)(g + c4);
    const float4 bv = *(const float4*)(beta + c4);
    const float y0 = (x0 - mean) * rs * gv.x + bv.x;
    const float y1 = (x1 - mean) * rs * gv.y + bv.y;
    const float y2 = (x2 - mean) * rs * gv.z + bv.z;
    const float y3 = (x3 - mean) * rs * gv.w + bv.w;
    if (HASF) {
        float4 o4; o4.x = y0; o4.y = y1; o4.z = y2; o4.w = y3;
        *(float4*)(outF + (size_t)row * 256 + c4) = o4;
    }
    if (HASB) {
        uint2 o2;
        o2.x = (unsigned)f2bf(y0) | ((unsigned)f2bf(y1) << 16);
        o2.y = (unsigned)f2bf(y2) | ((unsigned)f2bf(y3) << 16);
        *(uint2*)(outB + (size_t)row * 256 + c4) = o2;
    }
}

// ---------------------------------------------------------------------------
// fp32 [M,256] -> bf16 [M_PAD,256] with zero padding rows (layer 0 only)
// ---------------------------------------------------------------------------
__global__ __launch_bounds__(256)
void convpad(const float* __restrict__ X, unsigned short* __restrict__ Y, int M)
{
    const int idx = blockIdx.x * 256 + threadIdx.x;
    const int row = idx >> 6;
    const int c4  = (idx & 63) << 2;
    if (row >= M_PAD) return;
    float4 v = {0.f, 0.f, 0.f, 0.f};
    if (row < M) v = ((const float4*)(X + (size_t)row * 256))[c4 >> 2];
    unsigned p0 = (unsigned)f2bf(v.x) | ((unsigned)f2bf(v.y) << 16);
    unsigned p1 = (unsigned)f2bf(v.z) | ((unsigned)f2bf(v.w) << 16);
    uint2 o; o.x = p0; o.y = p1;
    *(uint2*)(Y + (size_t)row * 256 + c4) = o;
}

// ---------------------------------------------------------------------------
// Merged weight transpose+convert (12 segments, one dispatch).
// ---------------------------------------------------------------------------
struct WJobs {
    const float* W[12];
    unsigned short* WT[12];
    int K[12], N[12], tx[12], start[12];
};

__global__ __launch_bounds__(256)
void wtrans_all(WJobs jb)
{
    __shared__ float t[32][33];
    const int bx = blockIdx.x;
    int seg = 0;
    #pragma unroll
    for (int s = 1; s < 12; ++s) if (bx >= jb.start[s]) seg = s;
    const float* W = jb.W[seg];
    unsigned short* WT = jb.WT[seg];
    const int K = jb.K[seg], N = jb.N[seg], tx = jb.tx[seg];
    const int local = bx - jb.start[seg];
    const int n0 = (local % tx) * 32, k0 = (local / tx) * 32;
    const int c = threadIdx.x & 31, r0 = threadIdx.x >> 5;
    #pragma unroll
    for (int rr = r0; rr < 32; rr += 8)
        t[rr][c] = W[(size_t)(k0 + rr) * N + n0 + c];
    __syncthreads();
    #pragma unroll
    for (int rr = r0; rr < 32; rr += 8)
        WT[(size_t)(n0 + rr) * K + k0 + c] = f2bf(t[c][rr]);
}

// ---------------------------------------------------------------------------
// MSDA, 2-phase. XCD-swizzled block id (grid padded to 3328 = 8*416 so
// same-XCD blocks cover contiguous query ranges under round-robin dispatch).
// Phase B: raw-reinterpret hi-bf16 unpack (no AND), packed float2 fma.
// ---------------------------------------------------------------------------
__global__ __launch_bounds__(256)
void msda_kernel(const unsigned short* __restrict__ valb,
                 const unsigned short* __restrict__ oab,   // [M,384] bf16
                 const float* __restrict__ vr,
                 unsigned short* __restrict__ out)
{
    __shared__ __align__(16) char smeta[8 * 128 * 32];
    const int t = threadIdx.x;
    // XCD swizzle: consecutive blocks round-robin across 8 XCDs; remap so
    // blocks sharing an XCD handle adjacent queries (value-gather L2 reuse).
    const int bid = (blockIdx.x & 7) * 416 + (blockIdx.x >> 3);

    {
        const int wv = t >> 6, lane = t & 63;
        const int lqA = wv * 2 + (lane >> 5);
        const int bq = bid * 8 + lqA;
        const int h = (lane >> 2) & 7;
        const int j = lane & 3;
        if (bq < M_TOT) {
            const int b = (bq >= S_TOT) ? 1 : 0;
            const int q = bq - b * S_TOT;
            const int bofs = b * (S_TOT * 512);
            int Hq, rr, cc, lq;
            if (q < 10000)      { lq = 0; Hq = 100; rr = q / 100;              cc = q - rr * 100; }
            else if (q < 12500) { lq = 1; Hq = 50;  int r2 = q - 10000; rr = r2 / 50; cc = r2 - rr * 50; }
            else if (q < 13125) { lq = 2; Hq = 25;  int r2 = q - 12500; rr = r2 / 25; cc = r2 - rr * 25; }
            else                { lq = 3; Hq = 13;  int r2 = q - 13125; rr = r2 / 13; cc = r2 - rr * 13; }
            const float rxb = (cc + 0.5f) / (vr[(b * 4 + lq) * 2 + 0] * (float)Hq);
            const float ryb = (rr + 0.5f) / (vr[(b * 4 + lq) * 2 + 1] * (float)Hq);
            const int HWt[4] = {100, 50, 25, 13};
            const int stt[4] = {0, 10000, 12500, 13125};
            const int HW = HWt[j], st = stt[j];
            const float fW = (float)HW;
            const float refxw = rxb * vr[(b * 4 + j) * 2 + 0] * fW - 0.5f;
            const float refyw = ryb * vr[(b * 4 + j) * 2 + 1] * fW - 0.5f;
            const unsigned short* row = oab + (size_t)bq * 384;
            const uint2 lgu = *(const uint2*)(row + 256 + h * 16 + j * 4);
            const float l0 = bflo(lgu.x), l1 = bfhi(lgu.x);
            const float l2 = bflo(lgu.y), l3 = bfhi(lgu.y);
            float mx = fmaxf(fmaxf(l0, l1), fmaxf(l2, l3));
            mx = fmaxf(mx, __shfl_xor(mx, 1, 64));
            mx = fmaxf(mx, __shfl_xor(mx, 2, 64));
            const float e0 = __expf(l0 - mx), e1 = __expf(l1 - mx);
            const float e2 = __expf(l2 - mx), e3 = __expf(l3 - mx);
            float ss = e0 + e1 + e2 + e3;
            ss += __shfl_xor(ss, 1, 64);
            ss += __shfl_xor(ss, 2, 64);
            const float inv = 1.0f / ss;
            const uint4 ou = *(const uint4*)(row + h * 32 + j * 8);
            const float oxs[4] = {bflo(ou.x), bflo(ou.y), bflo(ou.z), bflo(ou.w)};
            const float oys[4] = {bfhi(ou.x), bfhi(ou.y), bfhi(ou.z), bfhi(ou.w)};
            const float aw[4]  = {e0 * inv, e1 * inv, e2 * inv, e3 * inv};
            char* mb = smeta + (size_t)(lqA * 128 + h * 16 + j * 4) * 32;
            const int swz = ((h * 4 + j) & 7) << 4;
            #pragma unroll
            for (int p = 0; p < 4; ++p) {
                const float x = refxw + oxs[p];
                const float y = refyw + oys[p];
                const float x0f = floorf(x), y0f = floorf(y);
                const int x0 = (int)x0f, y0 = (int)y0f;
                const float fx = x - x0f, fy = y - y0f;
                const float wb[4] = {(1.f - fx) * (1.f - fy), fx * (1.f - fy),
                                     (1.f - fx) * fy,         fx * fy};
                const int xs[2] = {x0, x0 + 1};
                const int ys2[2] = {y0, y0 + 1};
                int iv[4]; float wv4[4];
                #pragma unroll
                for (int k = 0; k < 4; ++k) {
                    const int xi = xs[k & 1], yi = ys2[k >> 1];
                    const bool vld = ((unsigned)xi < (unsigned)HW) && ((unsigned)yi < (unsigned)HW);
                    const int xc = min(max(xi, 0), HW - 1);
                    const int yc = min(max(yi, 0), HW - 1);
                    iv[k] = bofs + ((st + yc * HW + xc) << 9) + (h << 6);
                    wv4[k] = vld ? wb[k] * aw[p] : 0.0f;
                }
                int4 i4; i4.x = iv[0]; i4.y = iv[1]; i4.z = iv[2]; i4.w = iv[3];
                float4 w4; w4.x = wv4[0]; w4.y = wv4[1]; w4.z = wv4[2]; w4.w = wv4[3];
                *(int4*)(mb + ((p * 32) ^ swz)) = i4;
                *(float4*)(mb + ((p * 32 + 16) ^ swz)) = w4;
            }
        }
    }
    __syncthreads();
    {
        const int lq2 = t >> 5;
        const int r = t & 31;
        const int h2 = r >> 2;
        const int cg = r & 3;
        const int bq2 = bid * 8 + lq2;
        if (bq2 < M_TOT) {
            const char* vbase = (const char*)valb;
            const unsigned cgo = cg * 16;
            floatx2 a0 = {0.f, 0.f}, a1 = {0.f, 0.f}, a2 = {0.f, 0.f}, a3 = {0.f, 0.f};
            const char* mb2 = smeta + (size_t)(lq2 * 128 + h2 * 16) * 32;
            #pragma unroll 4
            for (int s = 0; s < 16; ++s) {
                const int swz2 = ((h2 * 4 + (s >> 2)) & 7) << 4;
                const int4  iv = *(const int4*)(mb2 + ((s * 32) ^ swz2));
                const float4 w4 = *(const float4*)(mb2 + ((s * 32 + 16) ^ swz2));
                const uint4 u0 = *(const uint4*)(vbase + (unsigned)(iv.x + cgo));
                const uint4 u1 = *(const uint4*)(vbase + (unsigned)(iv.y + cgo));
                const uint4 u2 = *(const uint4*)(vbase + (unsigned)(iv.z + cgo));
                const uint4 u3 = *(const uint4*)(vbase + (unsigned)(iv.w + cgo));
                // lo channel: exact (shift); hi channel: raw reinterpret —
                // low-half mantissa garbage is below bf16 rounding scale.
                #define ACC8(UU, WW) { \
                    const floatx2 w2 = {WW, WW}; \
                    const floatx2 t0 = {bflo(UU.x), braw(UU.x)}; \
                    const floatx2 t1 = {bflo(UU.y), braw(UU.y)}; \
                    const floatx2 t2 = {bflo(UU.z), braw(UU.z)}; \
                    const floatx2 t3 = {bflo(UU.w), braw(UU.w)}; \
                    a0 += w2 * t0; a1 += w2 * t1; a2 += w2 * t2; a3 += w2 * t3; }
                ACC8(u0, w4.x) ACC8(u1, w4.y) ACC8(u2, w4.z) ACC8(u3, w4.w)
                #undef ACC8
            }
            uint4 o;
            o.x = (unsigned)f2bf(a0.x) | ((unsigned)f2bf(a0.y) << 16);
            o.y = (unsigned)f2bf(a1.x) | ((unsigned)f2bf(a1.y) << 16);
            o.z = (unsigned)f2bf(a2.x) | ((unsigned)f2bf(a2.y) << 16);
            o.w = (unsigned)f2bf(a3.x) | ((unsigned)f2bf(a3.y) << 16);
            *(uint4*)(out + (size_t)bq2 * 256 + h2 * 32 + cg * 8) = o;
        }
    }
}

// ---------------------------------------------------------------------------
// Host-side orchestration
// ---------------------------------------------------------------------------
extern "C" void kernel_launch(void* const* d_in, const int* in_sizes, int n_in,
                              void* d_out, int out_size, void* d_ws, size_t ws_size,
                              hipStream_t stream)
{
    const float* src    = (const float*)d_in[0];
    const float* vr     = (const float*)d_in[2];
    const float* W_off  = (const float*)d_in[3];
    const float* b_off  = (const float*)d_in[4];
    const float* W_attn = (const float*)d_in[5];
    const float* b_attn = (const float*)d_in[6];
    const float* W_val  = (const float*)d_in[7];
    const float* b_val  = (const float*)d_in[8];
    const float* W_out  = (const float*)d_in[9];
    const float* b_out  = (const float*)d_in[10];
    const float* ln1_g  = (const float*)d_in[11];
    const float* ln1_b  = (const float*)d_in[12];
    const float* W1     = (const float*)d_in[13];
    const float* b1     = (const float*)d_in[14];
    const float* W2     = (const float*)d_in[15];
    const float* b2     = (const float*)d_in[16];
    const float* ln2_g  = (const float*)d_in[17];
    const float* ln2_b  = (const float*)d_in[18];
    float* out = (float*)d_out;

    const int M = M_TOT;

    // --- workspace (bytes), total 112,066,560 ---
    // [0,          54,525,952)  HBF bf16 [M_PAD,1024]; overlays:
    //     OAB  bf16 [M_PAD,384] at [0, 20,447,232)
    //     VALB bf16 [M_PAD,256] at [20,447,232, 34,078,720)
    //     S1   bf16 [M_PAD,256] at [0, 13,631,488)  (out-proj sum;
    //         lives between msda (OAB dead) and FFN1 (HBF write))
    // [54,525,952, 68,157,440)  X1B bf16 [M_PAD,256]  (post-LN1, bf16)
    // [68,157,440, 81,788,928)  S2  bf16 [M_PAD,256]  (FFN2 sum)
    // [81,788,928, 95,420,416)  RB  bf16 [M_PAD,256]  (x input, bf16)
    // [95,420,416,109,051,904)  YBF bf16 [M_PAD,256]  (msda out)
    // [109,051,904,112,066,560) WT  transposed weights
    char* wsb = (char*)d_ws;
    unsigned short* HBF  = (unsigned short*)wsb;
    unsigned short* OAB  = (unsigned short*)wsb;
    unsigned short* VALB = (unsigned short*)(wsb + 20447232);
    unsigned short* S1   = (unsigned short*)wsb;
    unsigned short* X1B  = (unsigned short*)(wsb + 54525952);
    unsigned short* S2   = (unsigned short*)(wsb + 68157440);
    unsigned short* RB   = (unsigned short*)(wsb + 81788928);
    unsigned short* YBF  = (unsigned short*)(wsb + 95420416);
    unsigned short* WT   = (unsigned short*)(wsb + 109051904);

    const size_t LWT = 753664;
    const size_t oProj = 0, oOut = 163840, oW1 = 229376, oW2 = 491520;

    WJobs jb;
    int startAcc = 0;
    for (int i = 0; i < 2; ++i) {
        unsigned short* wt = WT + i * LWT;
        const float* srcs[6] = {W_val + i * 65536, W_off + i * 65536, W_attn + i * 32768,
                                W_out + i * 65536, W1 + i * 262144, W2 + i * 262144};
        unsigned short* dsts[6] = {wt + oProj, wt + oProj + 65536, wt + oProj + 131072,
                                   wt + oOut, wt + oW1, wt + oW2};
        const int Ks[6] = {256, 256, 256, 256, 256, 1024};
        const int Ns[6] = {256, 256, 128, 256, 1024, 256};
        for (int s = 0; s < 6; ++s) {
            const int idx = i * 6 + s;
            jb.W[idx] = srcs[s]; jb.WT[idx] = dsts[s];
            jb.K[idx] = Ks[s]; jb.N[idx] = Ns[s]; jb.tx[idx] = Ns[s] / 32;
            jb.start[idx] = startAcc;
            startAcc += (Ns[s] / 32) * (Ks[s] / 32);
        }
    }
    wtrans_all<<<dim3(startAcc), 256, 0, stream>>>(jb);

    const int GM128 = M_PAD / 128;  // 208
    const int GM64  = M_PAD / 64;   // 416
    const int GLN   = M_TOT / 4;    // 6647 (26588 = 4*6647)
    const dim3 blk(256);

    for (int i = 0; i < 2; ++i) {
        unsigned short* wt = WT + i * LWT;

        if (i == 0)
            convpad<<<dim3(M_PAD / 4), blk, 0, stream>>>(src, RB, M);

        // merged projections: N=640 -> VALB (bf16) + OAB (bf16)
        // grid 5*416 blocks 1-D, nbmPer = 416/8 = 52
        mgemm<64, false, false, true, false><<<dim3(5 * GM64), blk, 0, stream>>>(
            RB, wt + oProj, b_val + i * 256, b_off + i * 256, b_attn + i * 128,
            nullptr, VALB, OAB, GM64 / 8, M, 640, 256);

        // deformable sampling (grid padded to 8*416 for the XCD swizzle)
        msda_kernel<<<dim3(3328), blk, 0, stream>>>(VALB, OAB, vr, YBF);

        // out-proj GEMM + bias + residual(RB) -> S1 bf16 (832 blocks)
        mgemm<64, false, false, false, true><<<dim3(2 * GM64), blk, 0, stream>>>(
            YBF, wt + oOut, b_out + i * 256, nullptr, nullptr,
            RB, S1, nullptr, GM64 / 8, M, 256, 256);

        // LN1: normalize S1 -> X1B bf16 (streaming, 1 wave/row)
        ln_kernel<false, true><<<dim3(GLN), blk, 0, stream>>>(
            S1, ln1_g + i * 256, ln1_b + i * 256, nullptr, X1B, M);

        // FFN1 (relu, bf16 hidden; 1664 blocks, nbmPer = 208/8 = 26)
        mgemm<128, true, true, false, false><<<dim3(8 * GM128), blk, 0, stream>>>(
            X1B, wt + oW1, b1 + i * 1024, nullptr, nullptr,
            nullptr, HBF, nullptr, GM128 / 8, M, 1024, 256);

        // FFN2 GEMM + bias + residual(X1B) -> S2 bf16
        mgemm<64, false, false, false, true><<<dim3(2 * GM64), blk, 0, stream>>>(
            HBF, wt + oW2, b2 + i * 256, nullptr, nullptr,
            X1B, S2, nullptr, GM64 / 8, M, 256, 1024);

        // LN2: normalize S2:
        //   layer 0 -> RB (bf16, next layer's x); layer 1 -> out (f32)
        if (i == 0)
            ln_kernel<false, true><<<dim3(GLN), blk, 0, stream>>>(
                S2, ln2_g + i * 256, ln2_b + i * 256, nullptr, RB, M);
        else
            ln_kernel<true, false><<<dim3(GLN), blk, 0, stream>>>(
                S2, ln2_g + i * 256, ln2_b + i * 256, out, nullptr, M);
    }
}

// Round 14
// 388.267 us; speedup vs baseline: 1.0428x; 1.0428x over previous
//
#include <hip/hip_runtime.h>
#include <math.h>

// Deformable-DETR encoder, 2 layers. Round 26: revert R25's dbuf (hurt:
// 394.7 -> 404.9; halving blocks/CU lost more cross-block TLP than the
// in-block pipeline gained -- R15+R25 together show co-resident-block
// overlap IS the latency hiding for these small-K GEMMs) back to R24's
// single-buffered mgemm. One low-risk tweak kept: ln_kernel at 16B/lane
// (half-wave per row, 8 rows/block) per guideline G13.

#define S_TOT 13294
#define BATCH 2
#define M_TOT (BATCH * S_TOT)     // 26588
#define M_PAD 26624               // 208*128 = 416*64

typedef __attribute__((ext_vector_type(8))) short short8;
typedef __attribute__((ext_vector_type(4))) float floatx4;
typedef __attribute__((ext_vector_type(2))) float floatx2;

#define AS1C(p) ((const __attribute__((address_space(1))) void*)(p))
#define AS3(p)  ((__attribute__((address_space(3))) void*)(p))

static __device__ __forceinline__ unsigned short f2bf(float x) {
    union { float f; unsigned u; } v; v.f = x;
    unsigned r = v.u + 0x7FFFu + ((v.u >> 16) & 1u);
    return (unsigned short)(r >> 16);
}
static __device__ __forceinline__ float b2f(unsigned short u) {
    union { unsigned u; float f; } v; v.u = (unsigned)u << 16; return v.f;
}
static __device__ __forceinline__ float bflo(unsigned u) {
    union { unsigned u; float f; } v; v.u = u << 16; return v.f;
}
static __device__ __forceinline__ float bfhi(unsigned u) {
    union { unsigned u; float f; } v; v.u = u & 0xFFFF0000u; return v.f;
}
// hi bf16 with low-half mantissa garbage (<=2^-7 rel, below bf16 rounding
// scale for our magnitudes) — saves the AND.
static __device__ __forceinline__ float braw(unsigned u) {
    union { unsigned u; float f; } v; v.u = u; return v.f;
}

// ---------------------------------------------------------------------------
// bf16 MFMA GEMM, BK=64, single-buffered (R24-proven: cross-block TLP at
// 4-6 blocks/CU hides the stage latency; dbuf variants regress).
// 1-D grid, XCD-swizzled decode: id&7 = XCD owns a contiguous bm range
// for ALL bn so the A-panel is fetched into that XCD's L2 once.
// TM=128: 4 waves 2x2 of 64x64. TM=64: 4 waves 64x32.
// PROJ: col<256 -> bf16 Cb[.,256]; col>=256 -> bf16 Cb2[.,384].
// SUM:  bf16 out = acc + bias + residual R (pre-LN sum, single [M,256]).
// ---------------------------------------------------------------------------
template<int TM, bool RELU, bool BF16OUT, bool PROJ, bool SUM>
__global__ __launch_bounds__(256)
void mgemm(const unsigned short* __restrict__ A,
           const unsigned short* __restrict__ BT,
           const float* __restrict__ bias,
           const float* __restrict__ bias2,
           const float* __restrict__ bias3,
           const unsigned short* __restrict__ R,   // bf16 residual [M_PAD,256]
           unsigned short* __restrict__ Cb,
           unsigned short* __restrict__ Cb2,
           int nbmPer,          // (M_PAD/TM)/8
           int M, int N, int K)
{
    constexpr int WM = (TM == 128) ? 2 : 1;
    constexpr int WN = 4 / WM;
    constexpr int MI = TM / (WM * 16);
    constexpr int NI = 128 / (WN * 16);
    __shared__ __align__(16) unsigned short smemA[2 * TM * 32];
    __shared__ __align__(16) unsigned short smemB[2 * 128 * 32];
    const int tid  = threadIdx.x;
    const int lane = tid & 63;
    const int w    = tid >> 6;
    const int wm   = w % WM, wn = w / WM;
    const int lr   = lane & 15, quad = lane >> 4;
    // XCD swizzle: consecutive ids round-robin XCDs; give XCD x a
    // contiguous bm chunk across all bn.
    const int id  = blockIdx.x;
    const int x8  = id & 7;
    const int k9  = id >> 3;
    const int bm  = (x8 * nbmPer + (k9 % nbmPer)) * TM;
    const int bn  = (k9 / nbmPer) * 128;

    floatx4 acc[MI][NI];
    #pragma unroll
    for (int i = 0; i < MI; ++i)
        #pragma unroll
        for (int j = 0; j < NI; ++j)
            acc[i][j] = (floatx4){0.f, 0.f, 0.f, 0.f};

    const int srow = lane >> 2;
    const int selt = (lane & 3) << 3;

    for (int k0 = 0; k0 < K; k0 += 64) {
        #pragma unroll
        for (int c = 0; c < 2; ++c) {
            if (TM == 128) {
                #pragma unroll
                for (int jj = 0; jj < 2; ++jj) {
                    const int j = 2 * w + jj;
                    const unsigned short* ga = A  + (size_t)(bm + j * 16 + srow) * K + k0 + c * 32 + selt;
                    const unsigned short* gb = BT + (size_t)(bn + j * 16 + srow) * K + k0 + c * 32 + selt;
                    __builtin_amdgcn_global_load_lds(AS1C(ga), AS3(smemA + c * (TM * 32) + j * 512), 16, 0, 0);
                    __builtin_amdgcn_global_load_lds(AS1C(gb), AS3(smemB + c * 4096 + j * 512), 16, 0, 0);
                }
            } else {
                const unsigned short* ga = A + (size_t)(bm + w * 16 + srow) * K + k0 + c * 32 + selt;
                __builtin_amdgcn_global_load_lds(AS1C(ga), AS3(smemA + c * (TM * 32) + w * 512), 16, 0, 0);
                #pragma unroll
                for (int jj = 0; jj < 2; ++jj) {
                    const int j = 2 * w + jj;
                    const unsigned short* gb = BT + (size_t)(bn + j * 16 + srow) * K + k0 + c * 32 + selt;
                    __builtin_amdgcn_global_load_lds(AS1C(gb), AS3(smemB + c * 4096 + j * 512), 16, 0, 0);
                }
            }
        }
        __syncthreads();

        #pragma unroll
        for (int c = 0; c < 2; ++c) {
            short8 av[MI], bv[NI];
            #pragma unroll
            for (int mi = 0; mi < MI; ++mi)
                av[mi] = *(const short8*)&smemA[c * (TM * 32) + (wm * MI * 16 + mi * 16 + lr) * 32 + quad * 8];
            #pragma unroll
            for (int ni = 0; ni < NI; ++ni)
                bv[ni] = *(const short8*)&smemB[c * 4096 + (wn * NI * 16 + ni * 16 + lr) * 32 + quad * 8];
            #pragma unroll
            for (int mi = 0; mi < MI; ++mi)
                #pragma unroll
                for (int ni = 0; ni < NI; ++ni)
                    acc[mi][ni] = __builtin_amdgcn_mfma_f32_16x16x32_bf16(
                        av[mi], bv[ni], acc[mi][ni], 0, 0, 0);
        }
        __syncthreads();
    }

    #pragma unroll
    for (int mi = 0; mi < MI; ++mi) {
        #pragma unroll
        for (int ni = 0; ni < NI; ++ni) {
            #pragma unroll
            for (int r = 0; r < 4; ++r) {
                const int row = bm + wm * MI * 16 + mi * 16 + quad * 4 + r;
                const int col = bn + wn * NI * 16 + ni * 16 + lr;
                if (PROJ) {
                    const float bb = (col < 256) ? bias[col]
                                   : (col < 512) ? bias2[col - 256]
                                                 : bias3[col - 512];
                    const float v = acc[mi][ni][r] + bb;
                    if (col < 256) Cb[(size_t)row * 256 + col] = f2bf(v);
                    else           Cb2[(size_t)row * 384 + (col - 256)] = f2bf(v);
                } else if (SUM) {
                    const float v = acc[mi][ni][r] + bias[col]
                                  + b2f(R[(size_t)row * 256 + col]);
                    Cb[(size_t)row * 256 + col] = f2bf(v);
                } else {
                    float v = acc[mi][ni][r] + bias[col];
                    if (RELU) v = fmaxf(v, 0.0f);
                    if (BF16OUT) Cb[(size_t)row * N + col] = f2bf(v);
                }
            }
        }
    }
}

// ---------------------------------------------------------------------------
// Streaming LayerNorm over the pre-computed bf16 sum S [M,256] (residual
// already folded in by the GEMM epilogue). Half-wave per row: 32 lanes x
// 8 bf16 = 16B/lane (G13 sweet spot); 8 rows per 256-thread block.
// shfl_xor offsets 1..16 reduce within each 32-lane half. 3324 blocks.
// ---------------------------------------------------------------------------
template<bool HASF, bool HASB>
__global__ __launch_bounds__(256)
void ln_kernel(const unsigned short* __restrict__ S,
               const float* __restrict__ g, const float* __restrict__ beta,
               float* __restrict__ outF, unsigned short* __restrict__ outB,
               int M)
{
    const int half = (threadIdx.x & 63) >> 5;   // 0 or 1 within the wave
    const int l32  = threadIdx.x & 31;
    const int row  = blockIdx.x * 8 + (threadIdx.x >> 6) * 2 + half;
    if (row >= M) return;
    const int c8 = l32 * 8;
    const uint4 sv = *(const uint4*)(S + (size_t)row * 256 + c8);
    float x[8];
    x[0] = bflo(sv.x); x[1] = bfhi(sv.x);
    x[2] = bflo(sv.y); x[3] = bfhi(sv.y);
    x[4] = bflo(sv.z); x[5] = bfhi(sv.z);
    x[6] = bflo(sv.w); x[7] = bfhi(sv.w);
    float p = 0.f, q = 0.f;
    #pragma unroll
    for (int i = 0; i < 8; ++i) { p += x[i]; q += x[i] * x[i]; }
    #pragma unroll
    for (int o = 1; o < 32; o <<= 1) {
        p += __shfl_xor(p, o, 64);
        q += __shfl_xor(q, o, 64);
    }
    const float mean = p * (1.0f / 256.0f);
    const float var  = q * (1.0f / 256.0f) - mean * mean;
    const float rs   = rsqrtf(var + 1e-5f);
    const float4 gv0 = *(const float4*)(g + c8);
    const float4 gv1 = *(const float4*)(g + c8 + 4);
    const float4 bv0 = *(const float4*)(beta + c8);
    const float4 bv1 = *(const float4*)(beta + c8 + 4);
    const float gg[8] = {gv0.x, gv0.y, gv0.z, gv0.w, gv1.x, gv1.y, gv1.z, gv1.w};
    const float bb[8] = {bv0.x, bv0.y, bv0.z, bv0.w, bv1.x, bv1.y, bv1.z, bv1.w};
    float y[8];
    #pragma unroll
    for (int i = 0; i < 8; ++i)
        y[i] = (x[i] - mean) * rs * gg[i] + bb[i];
    if (HASF) {
        float4 o0; o0.x = y[0]; o0.y = y[1]; o0.z = y[2]; o0.w = y[3];
        float4 o1; o1.x = y[4]; o1.y = y[5]; o1.z = y[6]; o1.w = y[7];
        *(float4*)(outF + (size_t)row * 256 + c8) = o0;
        *(float4*)(outF + (size_t)row * 256 + c8 + 4) = o1;
    }
    if (HASB) {
        uint4 o2;
        o2.x = (unsigned)f2bf(y[0]) | ((unsigned)f2bf(y[1]) << 16);
        o2.y = (unsigned)f2bf(y[2]) | ((unsigned)f2bf(y[3]) << 16);
        o2.z = (unsigned)f2bf(y[4]) | ((unsigned)f2bf(y[5]) << 16);
        o2.w = (unsigned)f2bf(y[6]) | ((unsigned)f2bf(y[7]) << 16);
        *(uint4*)(outB + (size_t)row * 256 + c8) = o2;
    }
}

// ---------------------------------------------------------------------------
// fp32 [M,256] -> bf16 [M_PAD,256] with zero padding rows (layer 0 only)
// ---------------------------------------------------------------------------
__global__ __launch_bounds__(256)
void convpad(const float* __restrict__ X, unsigned short* __restrict__ Y, int M)
{
    const int idx = blockIdx.x * 256 + threadIdx.x;
    const int row = idx >> 6;
    const int c4  = (idx & 63) << 2;
    if (row >= M_PAD) return;
    float4 v = {0.f, 0.f, 0.f, 0.f};
    if (row < M) v = ((const float4*)(X + (size_t)row * 256))[c4 >> 2];
    unsigned p0 = (unsigned)f2bf(v.x) | ((unsigned)f2bf(v.y) << 16);
    unsigned p1 = (unsigned)f2bf(v.z) | ((unsigned)f2bf(v.w) << 16);
    uint2 o; o.x = p0; o.y = p1;
    *(uint2*)(Y + (size_t)row * 256 + c4) = o;
}

// ---------------------------------------------------------------------------
// Merged weight transpose+convert (12 segments, one dispatch).
// ---------------------------------------------------------------------------
struct WJobs {
    const float* W[12];
    unsigned short* WT[12];
    int K[12], N[12], tx[12], start[12];
};

__global__ __launch_bounds__(256)
void wtrans_all(WJobs jb)
{
    __shared__ float t[32][33];
    const int bx = blockIdx.x;
    int seg = 0;
    #pragma unroll
    for (int s = 1; s < 12; ++s) if (bx >= jb.start[s]) seg = s;
    const float* W = jb.W[seg];
    unsigned short* WT = jb.WT[seg];
    const int K = jb.K[seg], N = jb.N[seg], tx = jb.tx[seg];
    const int local = bx - jb.start[seg];
    const int n0 = (local % tx) * 32, k0 = (local / tx) * 32;
    const int c = threadIdx.x & 31, r0 = threadIdx.x >> 5;
    #pragma unroll
    for (int rr = r0; rr < 32; rr += 8)
        t[rr][c] = W[(size_t)(k0 + rr) * N + n0 + c];
    __syncthreads();
    #pragma unroll
    for (int rr = r0; rr < 32; rr += 8)
        WT[(size_t)(n0 + rr) * K + k0 + c] = f2bf(t[c][rr]);
}

// ---------------------------------------------------------------------------
// MSDA, 2-phase. XCD-swizzled block id (grid padded to 3328 = 8*416 so
// same-XCD blocks cover contiguous query ranges under round-robin dispatch).
// Phase B: raw-reinterpret hi-bf16 unpack (no AND), packed float2 fma.
// ---------------------------------------------------------------------------
__global__ __launch_bounds__(256)
void msda_kernel(const unsigned short* __restrict__ valb,
                 const unsigned short* __restrict__ oab,   // [M,384] bf16
                 const float* __restrict__ vr,
                 unsigned short* __restrict__ out)
{
    __shared__ __align__(16) char smeta[8 * 128 * 32];
    const int t = threadIdx.x;
    // XCD swizzle: consecutive blocks round-robin across 8 XCDs; remap so
    // blocks sharing an XCD handle adjacent queries (value-gather L2 reuse).
    const int bid = (blockIdx.x & 7) * 416 + (blockIdx.x >> 3);

    {
        const int wv = t >> 6, lane = t & 63;
        const int lqA = wv * 2 + (lane >> 5);
        const int bq = bid * 8 + lqA;
        const int h = (lane >> 2) & 7;
        const int j = lane & 3;
        if (bq < M_TOT) {
            const int b = (bq >= S_TOT) ? 1 : 0;
            const int q = bq - b * S_TOT;
            const int bofs = b * (S_TOT * 512);
            int Hq, rr, cc, lq;
            if (q < 10000)      { lq = 0; Hq = 100; rr = q / 100;              cc = q - rr * 100; }
            else if (q < 12500) { lq = 1; Hq = 50;  int r2 = q - 10000; rr = r2 / 50; cc = r2 - rr * 50; }
            else if (q < 13125) { lq = 2; Hq = 25;  int r2 = q - 12500; rr = r2 / 25; cc = r2 - rr * 25; }
            else                { lq = 3; Hq = 13;  int r2 = q - 13125; rr = r2 / 13; cc = r2 - rr * 13; }
            const float rxb = (cc + 0.5f) / (vr[(b * 4 + lq) * 2 + 0] * (float)Hq);
            const float ryb = (rr + 0.5f) / (vr[(b * 4 + lq) * 2 + 1] * (float)Hq);
            const int HWt[4] = {100, 50, 25, 13};
            const int stt[4] = {0, 10000, 12500, 13125};
            const int HW = HWt[j], st = stt[j];
            const float fW = (float)HW;
            const float refxw = rxb * vr[(b * 4 + j) * 2 + 0] * fW - 0.5f;
            const float refyw = ryb * vr[(b * 4 + j) * 2 + 1] * fW - 0.5f;
            const unsigned short* row = oab + (size_t)bq * 384;
            const uint2 lgu = *(const uint2*)(row + 256 + h * 16 + j * 4);
            const float l0 = bflo(lgu.x), l1 = bfhi(lgu.x);
            const float l2 = bflo(lgu.y), l3 = bfhi(lgu.y);
            float mx = fmaxf(fmaxf(l0, l1), fmaxf(l2, l3));
            mx = fmaxf(mx, __shfl_xor(mx, 1, 64));
            mx = fmaxf(mx, __shfl_xor(mx, 2, 64));
            const float e0 = __expf(l0 - mx), e1 = __expf(l1 - mx);
            const float e2 = __expf(l2 - mx), e3 = __expf(l3 - mx);
            float ss = e0 + e1 + e2 + e3;
            ss += __shfl_xor(ss, 1, 64);
            ss += __shfl_xor(ss, 2, 64);
            const float inv = 1.0f / ss;
            const uint4 ou = *(const uint4*)(row + h * 32 + j * 8);
            const float oxs[4] = {bflo(ou.x), bflo(ou.y), bflo(ou.z), bflo(ou.w)};
            const float oys[4] = {bfhi(ou.x), bfhi(ou.y), bfhi(ou.z), bfhi(ou.w)};
            const float aw[4]  = {e0 * inv, e1 * inv, e2 * inv, e3 * inv};
            char* mb = smeta + (size_t)(lqA * 128 + h * 16 + j * 4) * 32;
            const int swz = ((h * 4 + j) & 7) << 4;
            #pragma unroll
            for (int p = 0; p < 4; ++p) {
                const float x = refxw + oxs[p];
                const float y = refyw + oys[p];
                const float x0f = floorf(x), y0f = floorf(y);
                const int x0 = (int)x0f, y0 = (int)y0f;
                const float fx = x - x0f, fy = y - y0f;
                const float wb[4] = {(1.f - fx) * (1.f - fy), fx * (1.f - fy),
                                     (1.f - fx) * fy,         fx * fy};
                const int xs[2] = {x0, x0 + 1};
                const int ys2[2] = {y0, y0 + 1};
                int iv[4]; float wv4[4];
                #pragma unroll
                for (int k = 0; k < 4; ++k) {
                    const int xi = xs[k & 1], yi = ys2[k >> 1];
                    const bool vld = ((unsigned)xi < (unsigned)HW) && ((unsigned)yi < (unsigned)HW);
                    const int xc = min(max(xi, 0), HW - 1);
                    const int yc = min(max(yi, 0), HW - 1);
                    iv[k] = bofs + ((st + yc * HW + xc) << 9) + (h << 6);
                    wv4[k] = vld ? wb[k] * aw[p] : 0.0f;
                }
                int4 i4; i4.x = iv[0]; i4.y = iv[1]; i4.z = iv[2]; i4.w = iv[3];
                float4 w4; w4.x = wv4[0]; w4.y = wv4[1]; w4.z = wv4[2]; w4.w = wv4[3];
                *(int4*)(mb + ((p * 32) ^ swz)) = i4;
                *(float4*)(mb + ((p * 32 + 16) ^ swz)) = w4;
            }
        }
    }
    __syncthreads();
    {
        const int lq2 = t >> 5;
        const int r = t & 31;
        const int h2 = r >> 2;
        const int cg = r & 3;
        const int bq2 = bid * 8 + lq2;
        if (bq2 < M_TOT) {
            const char* vbase = (const char*)valb;
            const unsigned cgo = cg * 16;
            floatx2 a0 = {0.f, 0.f}, a1 = {0.f, 0.f}, a2 = {0.f, 0.f}, a3 = {0.f, 0.f};
            const char* mb2 = smeta + (size_t)(lq2 * 128 + h2 * 16) * 32;
            #pragma unroll 4
            for (int s = 0; s < 16; ++s) {
                const int swz2 = ((h2 * 4 + (s >> 2)) & 7) << 4;
                const int4  iv = *(const int4*)(mb2 + ((s * 32) ^ swz2));
                const float4 w4 = *(const float4*)(mb2 + ((s * 32 + 16) ^ swz2));
                const uint4 u0 = *(const uint4*)(vbase + (unsigned)(iv.x + cgo));
                const uint4 u1 = *(const uint4*)(vbase + (unsigned)(iv.y + cgo));
                const uint4 u2 = *(const uint4*)(vbase + (unsigned)(iv.z + cgo));
                const uint4 u3 = *(const uint4*)(vbase + (unsigned)(iv.w + cgo));
                // lo channel: exact (shift); hi channel: raw reinterpret —
                // low-half mantissa garbage is below bf16 rounding scale.
                #define ACC8(UU, WW) { \
                    const floatx2 w2 = {WW, WW}; \
                    const floatx2 t0 = {bflo(UU.x), braw(UU.x)}; \
                    const floatx2 t1 = {bflo(UU.y), braw(UU.y)}; \
                    const floatx2 t2 = {bflo(UU.z), braw(UU.z)}; \
                    const floatx2 t3 = {bflo(UU.w), braw(UU.w)}; \
                    a0 += w2 * t0; a1 += w2 * t1; a2 += w2 * t2; a3 += w2 * t3; }
                ACC8(u0, w4.x) ACC8(u1, w4.y) ACC8(u2, w4.z) ACC8(u3, w4.w)
                #undef ACC8
            }
            uint4 o;
            o.x = (unsigned)f2bf(a0.x) | ((unsigned)f2bf(a0.y) << 16);
            o.y = (unsigned)f2bf(a1.x) | ((unsigned)f2bf(a1.y) << 16);
            o.z = (unsigned)f2bf(a2.x) | ((unsigned)f2bf(a2.y) << 16);
            o.w = (unsigned)f2bf(a3.x) | ((unsigned)f2bf(a3.y) << 16);
            *(uint4*)(out + (size_t)bq2 * 256 + h2 * 32 + cg * 8) = o;
        }
    }
}

// ---------------------------------------------------------------------------
// Host-side orchestration
// ---------------------------------------------------------------------------
extern "C" void kernel_launch(void* const* d_in, const int* in_sizes, int n_in,
                              void* d_out, int out_size, void* d_ws, size_t ws_size,
                              hipStream_t stream)
{
    const float* src    = (const float*)d_in[0];
    const float* vr     = (const float*)d_in[2];
    const float* W_off  = (const float*)d_in[3];
    const float* b_off  = (const float*)d_in[4];
    const float* W_attn = (const float*)d_in[5];
    const float* b_attn = (const float*)d_in[6];
    const float* W_val  = (const float*)d_in[7];
    const float* b_val  = (const float*)d_in[8];
    const float* W_out  = (const float*)d_in[9];
    const float* b_out  = (const float*)d_in[10];
    const float* ln1_g  = (const float*)d_in[11];
    const float* ln1_b  = (const float*)d_in[12];
    const float* W1     = (const float*)d_in[13];
    const float* b1     = (const float*)d_in[14];
    const float* W2     = (const float*)d_in[15];
    const float* b2     = (const float*)d_in[16];
    const float* ln2_g  = (const float*)d_in[17];
    const float* ln2_b  = (const float*)d_in[18];
    float* out = (float*)d_out;

    const int M = M_TOT;

    // --- workspace (bytes), total 112,066,560 ---
    // [0,          54,525,952)  HBF bf16 [M_PAD,1024]; overlays:
    //     OAB  bf16 [M_PAD,384] at [0, 20,447,232)
    //     VALB bf16 [M_PAD,256] at [20,447,232, 34,078,720)
    //     S1   bf16 [M_PAD,256] at [0, 13,631,488)  (out-proj sum;
    //         lives between msda (OAB dead) and FFN1 (HBF write))
    // [54,525,952, 68,157,440)  X1B bf16 [M_PAD,256]  (post-LN1, bf16)
    // [68,157,440, 81,788,928)  S2  bf16 [M_PAD,256]  (FFN2 sum)
    // [81,788,928, 95,420,416)  RB  bf16 [M_PAD,256]  (x input, bf16)
    // [95,420,416,109,051,904)  YBF bf16 [M_PAD,256]  (msda out)
    // [109,051,904,112,066,560) WT  transposed weights
    char* wsb = (char*)d_ws;
    unsigned short* HBF  = (unsigned short*)wsb;
    unsigned short* OAB  = (unsigned short*)wsb;
    unsigned short* VALB = (unsigned short*)(wsb + 20447232);
    unsigned short* S1   = (unsigned short*)wsb;
    unsigned short* X1B  = (unsigned short*)(wsb + 54525952);
    unsigned short* S2   = (unsigned short*)(wsb + 68157440);
    unsigned short* RB   = (unsigned short*)(wsb + 81788928);
    unsigned short* YBF  = (unsigned short*)(wsb + 95420416);
    unsigned short* WT   = (unsigned short*)(wsb + 109051904);

    const size_t LWT = 753664;
    const size_t oProj = 0, oOut = 163840, oW1 = 229376, oW2 = 491520;

    WJobs jb;
    int startAcc = 0;
    for (int i = 0; i < 2; ++i) {
        unsigned short* wt = WT + i * LWT;
        const float* srcs[6] = {W_val + i * 65536, W_off + i * 65536, W_attn + i * 32768,
                                W_out + i * 65536, W1 + i * 262144, W2 + i * 262144};
        unsigned short* dsts[6] = {wt + oProj, wt + oProj + 65536, wt + oProj + 131072,
                                   wt + oOut, wt + oW1, wt + oW2};
        const int Ks[6] = {256, 256, 256, 256, 256, 1024};
        const int Ns[6] = {256, 256, 128, 256, 1024, 256};
        for (int s = 0; s < 6; ++s) {
            const int idx = i * 6 + s;
            jb.W[idx] = srcs[s]; jb.WT[idx] = dsts[s];
            jb.K[idx] = Ks[s]; jb.N[idx] = Ns[s]; jb.tx[idx] = Ns[s] / 32;
            jb.start[idx] = startAcc;
            startAcc += (Ns[s] / 32) * (Ks[s] / 32);
        }
    }
    wtrans_all<<<dim3(startAcc), 256, 0, stream>>>(jb);

    const int GM128 = M_PAD / 128;  // 208
    const int GM64  = M_PAD / 64;   // 416
    const int GLN   = (M_TOT + 7) / 8;  // 3324
    const dim3 blk(256);

    for (int i = 0; i < 2; ++i) {
        unsigned short* wt = WT + i * LWT;

        if (i == 0)
            convpad<<<dim3(M_PAD / 4), blk, 0, stream>>>(src, RB, M);

        // merged projections: N=640 -> VALB (bf16) + OAB (bf16)
        // grid 5*416 blocks 1-D, nbmPer = 416/8 = 52
        mgemm<64, false, false, true, false><<<dim3(5 * GM64), blk, 0, stream>>>(
            RB, wt + oProj, b_val + i * 256, b_off + i * 256, b_attn + i * 128,
            nullptr, VALB, OAB, GM64 / 8, M, 640, 256);

        // deformable sampling (grid padded to 8*416 for the XCD swizzle)
        msda_kernel<<<dim3(3328), blk, 0, stream>>>(VALB, OAB, vr, YBF);

        // out-proj GEMM + bias + residual(RB) -> S1 bf16 (832 blocks)
        mgemm<64, false, false, false, true><<<dim3(2 * GM64), blk, 0, stream>>>(
            YBF, wt + oOut, b_out + i * 256, nullptr, nullptr,
            RB, S1, nullptr, GM64 / 8, M, 256, 256);

        // LN1: normalize S1 -> X1B bf16 (streaming, half-wave/row)
        ln_kernel<false, true><<<dim3(GLN), blk, 0, stream>>>(
            S1, ln1_g + i * 256, ln1_b + i * 256, nullptr, X1B, M);

        // FFN1 (relu, bf16 hidden; 1664 blocks, nbmPer = 208/8 = 26)
        mgemm<128, true, true, false, false><<<dim3(8 * GM128), blk, 0, stream>>>(
            X1B, wt + oW1, b1 + i * 1024, nullptr, nullptr,
            nullptr, HBF, nullptr, GM128 / 8, M, 1024, 256);

        // FFN2 GEMM + bias + residual(X1B) -> S2 bf16
        mgemm<64, false, false, false, true><<<dim3(2 * GM64), blk, 0, stream>>>(
            HBF, wt + oW2, b2 + i * 256, nullptr, nullptr,
            X1B, S2, nullptr, GM64 / 8, M, 256, 1024);

        // LN2: normalize S2:
        //   layer 0 -> RB (bf16, next layer's x); layer 1 -> out (f32)
        if (i == 0)
            ln_kernel<false, true><<<dim3(GLN), blk, 0, stream>>>(
                S2, ln2_g + i * 256, ln2_b + i * 256, nullptr, RB, M);
        else
            ln_kernel<true, false><<<dim3(GLN), blk, 0, stream>>>(
                S2, ln2_g + i * 256, ln2_b + i * 256, out, nullptr, M);
    }
}

// Round 17
// 376.718 us; speedup vs baseline: 1.0748x; 1.0307x over previous
//
#include <hip/hip_runtime.h>
#include <math.h>

// Deformable-DETR encoder, 2 layers. Round 29 = round 27 resubmitted again
// (two consecutive GPUAcquisitionTimeouts: broker at capacity, kernel never
// ran either time; precedent rounds 4->5, 7->8, 10->11 all ran clean on
// identical resubmit; ffn_fused audited twice, no fault path).
// FFN1+FFN2 fusion: R26 = 388.3 us (best). Remaining dominant traffic:
// the 54.5 MB bf16 hidden written by FFN1 and immediately re-read by
// FFN2, plus FFN2's 13.6 MB residual re-read (~244 MB round-trip).
// Fuse: per 64-row block (full N=256), process hidden in 16 chunks of
// 64 dims through LDS: GEMM1 chunk (K=256, W1 panel 32 KB) -> relu+bf16
// -> hbuf 8 KB -> GEMM2 accumulate (K=64, W2 panel 32 KB). Weights
// L2-served (shared by all 52 blocks/XCD via the swizzle); residual from
// the staged X tile. Numerics bit-equivalent. LDS 72 KB -> 2 blocks/CU;
// per-chunk stages hit L2 (~300 cy) not HBM. Everything else = R26.

#define S_TOT 13294
#define BATCH 2
#define M_TOT (BATCH * S_TOT)     // 26588
#define M_PAD 26624               // 208*128 = 416*64

typedef __attribute__((ext_vector_type(8))) short short8;
typedef __attribute__((ext_vector_type(4))) float floatx4;
typedef __attribute__((ext_vector_type(2))) float floatx2;

#define AS1C(p) ((const __attribute__((address_space(1))) void*)(p))
#define AS3(p)  ((__attribute__((address_space(3))) void*)(p))

static __device__ __forceinline__ unsigned short f2bf(float x) {
    union { float f; unsigned u; } v; v.f = x;
    unsigned r = v.u + 0x7FFFu + ((v.u >> 16) & 1u);
    return (unsigned short)(r >> 16);
}
static __device__ __forceinline__ float b2f(unsigned short u) {
    union { unsigned u; float f; } v; v.u = (unsigned)u << 16; return v.f;
}
static __device__ __forceinline__ float bflo(unsigned u) {
    union { unsigned u; float f; } v; v.u = u << 16; return v.f;
}
static __device__ __forceinline__ float bfhi(unsigned u) {
    union { unsigned u; float f; } v; v.u = u & 0xFFFF0000u; return v.f;
}
// hi bf16 with low-half mantissa garbage (<=2^-7 rel, below bf16 rounding
// scale for our magnitudes) — saves the AND.
static __device__ __forceinline__ float braw(unsigned u) {
    union { unsigned u; float f; } v; v.u = u; return v.f;
}

// ---------------------------------------------------------------------------
// bf16 MFMA GEMM, BK=64, single-buffered (R24-proven: cross-block TLP at
// 4-6 blocks/CU hides the stage latency; dbuf variants regress).
// 1-D grid, XCD-swizzled decode: id&7 = XCD owns a contiguous bm range.
// TM=128: 4 waves 2x2 of 64x64. TM=64: 4 waves 64x32.
// PROJ: col<256 -> bf16 Cb[.,256]; col>=256 -> bf16 Cb2[.,384].
// SUM:  bf16 out = acc + bias + residual R (pre-LN sum, single [M,256]).
// ---------------------------------------------------------------------------
template<int TM, bool RELU, bool BF16OUT, bool PROJ, bool SUM>
__global__ __launch_bounds__(256)
void mgemm(const unsigned short* __restrict__ A,
           const unsigned short* __restrict__ BT,
           const float* __restrict__ bias,
           const float* __restrict__ bias2,
           const float* __restrict__ bias3,
           const unsigned short* __restrict__ R,   // bf16 residual [M_PAD,256]
           unsigned short* __restrict__ Cb,
           unsigned short* __restrict__ Cb2,
           int nbmPer,          // (M_PAD/TM)/8
           int M, int N, int K)
{
    constexpr int WM = (TM == 128) ? 2 : 1;
    constexpr int WN = 4 / WM;
    constexpr int MI = TM / (WM * 16);
    constexpr int NI = 128 / (WN * 16);
    __shared__ __align__(16) unsigned short smemA[2 * TM * 32];
    __shared__ __align__(16) unsigned short smemB[2 * 128 * 32];
    const int tid  = threadIdx.x;
    const int lane = tid & 63;
    const int w    = tid >> 6;
    const int wm   = w % WM, wn = w / WM;
    const int lr   = lane & 15, quad = lane >> 4;
    const int id  = blockIdx.x;
    const int x8  = id & 7;
    const int k9  = id >> 3;
    const int bm  = (x8 * nbmPer + (k9 % nbmPer)) * TM;
    const int bn  = (k9 / nbmPer) * 128;

    floatx4 acc[MI][NI];
    #pragma unroll
    for (int i = 0; i < MI; ++i)
        #pragma unroll
        for (int j = 0; j < NI; ++j)
            acc[i][j] = (floatx4){0.f, 0.f, 0.f, 0.f};

    const int srow = lane >> 2;
    const int selt = (lane & 3) << 3;

    for (int k0 = 0; k0 < K; k0 += 64) {
        #pragma unroll
        for (int c = 0; c < 2; ++c) {
            if (TM == 128) {
                #pragma unroll
                for (int jj = 0; jj < 2; ++jj) {
                    const int j = 2 * w + jj;
                    const unsigned short* ga = A  + (size_t)(bm + j * 16 + srow) * K + k0 + c * 32 + selt;
                    const unsigned short* gb = BT + (size_t)(bn + j * 16 + srow) * K + k0 + c * 32 + selt;
                    __builtin_amdgcn_global_load_lds(AS1C(ga), AS3(smemA + c * (TM * 32) + j * 512), 16, 0, 0);
                    __builtin_amdgcn_global_load_lds(AS1C(gb), AS3(smemB + c * 4096 + j * 512), 16, 0, 0);
                }
            } else {
                const unsigned short* ga = A + (size_t)(bm + w * 16 + srow) * K + k0 + c * 32 + selt;
                __builtin_amdgcn_global_load_lds(AS1C(ga), AS3(smemA + c * (TM * 32) + w * 512), 16, 0, 0);
                #pragma unroll
                for (int jj = 0; jj < 2; ++jj) {
                    const int j = 2 * w + jj;
                    const unsigned short* gb = BT + (size_t)(bn + j * 16 + srow) * K + k0 + c * 32 + selt;
                    __builtin_amdgcn_global_load_lds(AS1C(gb), AS3(smemB + c * 4096 + j * 512), 16, 0, 0);
                }
            }
        }
        __syncthreads();

        #pragma unroll
        for (int c = 0; c < 2; ++c) {
            short8 av[MI], bv[NI];
            #pragma unroll
            for (int mi = 0; mi < MI; ++mi)
                av[mi] = *(const short8*)&smemA[c * (TM * 32) + (wm * MI * 16 + mi * 16 + lr) * 32 + quad * 8];
            #pragma unroll
            for (int ni = 0; ni < NI; ++ni)
                bv[ni] = *(const short8*)&smemB[c * 4096 + (wn * NI * 16 + ni * 16 + lr) * 32 + quad * 8];
            #pragma unroll
            for (int mi = 0; mi < MI; ++mi)
                #pragma unroll
                for (int ni = 0; ni < NI; ++ni)
                    acc[mi][ni] = __builtin_amdgcn_mfma_f32_16x16x32_bf16(
                        av[mi], bv[ni], acc[mi][ni], 0, 0, 0);
        }
        __syncthreads();
    }

    #pragma unroll
    for (int mi = 0; mi < MI; ++mi) {
        #pragma unroll
        for (int ni = 0; ni < NI; ++ni) {
            #pragma unroll
            for (int r = 0; r < 4; ++r) {
                const int row = bm + wm * MI * 16 + mi * 16 + quad * 4 + r;
                const int col = bn + wn * NI * 16 + ni * 16 + lr;
                if (PROJ) {
                    const float bb = (col < 256) ? bias[col]
                                   : (col < 512) ? bias2[col - 256]
                                                 : bias3[col - 512];
                    const float v = acc[mi][ni][r] + bb;
                    if (col < 256) Cb[(size_t)row * 256 + col] = f2bf(v);
                    else           Cb2[(size_t)row * 384 + (col - 256)] = f2bf(v);
                } else if (SUM) {
                    const float v = acc[mi][ni][r] + bias[col]
                                  + b2f(R[(size_t)row * 256 + col]);
                    Cb[(size_t)row * 256 + col] = f2bf(v);
                } else {
                    float v = acc[mi][ni][r] + bias[col];
                    if (RELU) v = fmaxf(v, 0.0f);
                    if (BF16OUT) Cb[(size_t)row * N + col] = f2bf(v);
                }
            }
        }
    }
}

// ---------------------------------------------------------------------------
// Fused FFN: S2 = relu(X@W1+b1)@W2 + b2 + X  (pre-LN2 sum, bf16).
// One 64-row block owns full N=256. X tile (32 KB) staged once; hidden
// processed in 16 chunks of 64 dims: GEMM1 (K=256, W1 panel 32 KB, L2-
// served) -> relu+bias -> hbuf bf16 (8 KB) -> GEMM2 accumulate (K=64,
// W2 panel 32 KB, L2-served). Residual from the staged X tile. 72 KB
// LDS, 416 blocks XCD-swizzled. Numerics identical to the de-fused
// path (same bf16 rounding of the hidden).
// ---------------------------------------------------------------------------
__global__ __launch_bounds__(256)
void ffn_fused(const unsigned short* __restrict__ X,    // X1B [M_PAD,256]
               const unsigned short* __restrict__ W1T,  // [1024,256]
               const float* __restrict__ b1,            // [1024]
               const unsigned short* __restrict__ W2T,  // [256,1024]
               const float* __restrict__ b2,            // [256]
               unsigned short* __restrict__ S2,         // [M_PAD,256]
               int nbmPer)                              // 52
{
    __shared__ __align__(16) unsigned short xs[16384];   // X [8c][64r][32]
    __shared__ __align__(16) unsigned short wbuf[16384]; // W1/W2 panel
    __shared__ __align__(16) unsigned short hbuf[4096];  // hidden [2c][64r][32]
    const int lane = threadIdx.x & 63;
    const int w    = threadIdx.x >> 6;
    const int lr   = lane & 15, quad = lane >> 4;
    const int srow = lane >> 2;
    const int selt = (lane & 3) << 3;
    const int id   = blockIdx.x;
    const int bm   = ((id & 7) * nbmPer + (id >> 3)) * 64;

    // stage X tile once: rows bm..bm+63, 256 cols (512 B/row)
    #pragma unroll
    for (int c = 0; c < 8; ++c) {
        const unsigned short* gx = X + (size_t)(bm + w * 16 + srow) * 256 + c * 32 + selt;
        __builtin_amdgcn_global_load_lds(AS1C(gx), AS3(xs + c * 2048 + w * 512), 16, 0, 0);
    }

    floatx4 acc2[4][4];
    #pragma unroll
    for (int i = 0; i < 4; ++i)
        #pragma unroll
        for (int j = 0; j < 4; ++j)
            acc2[i][j] = (floatx4){0.f, 0.f, 0.f, 0.f};

    for (int kc = 0; kc < 16; ++kc) {
        // stage W1 panel: rows kc*64..+64 of W1T[1024][256]
        #pragma unroll
        for (int c = 0; c < 8; ++c) {
            const unsigned short* g1 = W1T + (size_t)(kc * 64 + w * 16 + srow) * 256 + c * 32 + selt;
            __builtin_amdgcn_global_load_lds(AS1C(g1), AS3(wbuf + c * 2048 + w * 512), 16, 0, 0);
        }
        asm volatile("s_waitcnt vmcnt(0)" ::: "memory");   // W1 (and X, first iter) ready
        __builtin_amdgcn_s_barrier();

        // GEMM1: hidden chunk [64 rows][64 hdims], K=256.
        // wave w computes hidden cols w*16..+16 for all 64 rows.
        floatx4 acc1[4];
        #pragma unroll
        for (int mi = 0; mi < 4; ++mi) acc1[mi] = (floatx4){0.f, 0.f, 0.f, 0.f};
        #pragma unroll
        for (int kk = 0; kk < 8; ++kk) {
            const short8 bv = *(const short8*)&wbuf[kk * 2048 + (w * 16 + lr) * 32 + quad * 8];
            #pragma unroll
            for (int mi = 0; mi < 4; ++mi) {
                const short8 av = *(const short8*)&xs[kk * 2048 + (mi * 16 + lr) * 32 + quad * 8];
                acc1[mi] = __builtin_amdgcn_mfma_f32_16x16x32_bf16(av, bv, acc1[mi], 0, 0, 0);
            }
        }
        // relu(acc1 + b1) -> hbuf bf16. C-layout: row = mi*16+quad*4+r, col = lr.
        const float b1v = b1[kc * 64 + w * 16 + lr];
        {
            const int hcol = w * 16 + lr;
            const int hc   = (hcol >> 5) * 2048 + (hcol & 31);
            #pragma unroll
            for (int mi = 0; mi < 4; ++mi)
                #pragma unroll
                for (int r = 0; r < 4; ++r) {
                    const int hrow = mi * 16 + quad * 4 + r;
                    hbuf[hc + hrow * 32] = f2bf(fmaxf(acc1[mi][r] + b1v, 0.f));
                }
        }
        asm volatile("s_waitcnt lgkmcnt(0)" ::: "memory");  // wbuf reads + hbuf writes done
        __builtin_amdgcn_s_barrier();

        // stage W2 panel: all 256 rows of W2T[256][1024], k-chunk kc*64..+64
        #pragma unroll
        for (int c = 0; c < 2; ++c)
            #pragma unroll
            for (int jj = 0; jj < 4; ++jj) {
                const int j = w * 4 + jj;
                const unsigned short* g2 = W2T + (size_t)(j * 16 + srow) * 1024 + kc * 64 + c * 32 + selt;
                __builtin_amdgcn_global_load_lds(AS1C(g2), AS3(wbuf + c * 8192 + j * 512), 16, 0, 0);
            }
        asm volatile("s_waitcnt vmcnt(0)" ::: "memory");
        __builtin_amdgcn_s_barrier();

        // GEMM2: acc2 += hidden @ W2chunk. wave w owns out cols w*64..+64.
        #pragma unroll
        for (int kk = 0; kk < 2; ++kk) {
            short8 av2[4], bv2[4];
            #pragma unroll
            for (int mi = 0; mi < 4; ++mi)
                av2[mi] = *(const short8*)&hbuf[kk * 2048 + (mi * 16 + lr) * 32 + quad * 8];
            #pragma unroll
            for (int ni = 0; ni < 4; ++ni)
                bv2[ni] = *(const short8*)&wbuf[kk * 8192 + (w * 64 + ni * 16 + lr) * 32 + quad * 8];
            #pragma unroll
            for (int mi = 0; mi < 4; ++mi)
                #pragma unroll
                for (int ni = 0; ni < 4; ++ni)
                    acc2[mi][ni] = __builtin_amdgcn_mfma_f32_16x16x32_bf16(
                        av2[mi], bv2[ni], acc2[mi][ni], 0, 0, 0);
        }
        asm volatile("s_waitcnt lgkmcnt(0)" ::: "memory");  // hbuf/wbuf reads done
        __builtin_amdgcn_s_barrier();                       // before next chunk overwrites
    }

    // epilogue: S2 = acc2 + b2 + X (residual from staged xs)
    #pragma unroll
    for (int mi = 0; mi < 4; ++mi)
        #pragma unroll
        for (int ni = 0; ni < 4; ++ni)
            #pragma unroll
            for (int r = 0; r < 4; ++r) {
                const int row = mi * 16 + quad * 4 + r;
                const int col = w * 64 + ni * 16 + lr;
                const float resid = b2f(xs[(col >> 5) * 2048 + row * 32 + (col & 31)]);
                const float v = acc2[mi][ni][r] + b2[col] + resid;
                S2[(size_t)(bm + row) * 256 + col] = f2bf(v);
            }
}

// ---------------------------------------------------------------------------
// Streaming LayerNorm over the pre-computed bf16 sum S [M,256]. Half-wave
// per row: 32 lanes x 8 bf16 = 16B/lane; 8 rows per 256-thread block.
// ---------------------------------------------------------------------------
template<bool HASF, bool HASB>
__global__ __launch_bounds__(256)
void ln_kernel(const unsigned short* __restrict__ S,
               const float* __restrict__ g, const float* __restrict__ beta,
               float* __restrict__ outF, unsigned short* __restrict__ outB,
               int M)
{
    const int half = (threadIdx.x & 63) >> 5;   // 0 or 1 within the wave
    const int l32  = threadIdx.x & 31;
    const int row  = blockIdx.x * 8 + (threadIdx.x >> 6) * 2 + half;
    if (row >= M) return;
    const int c8 = l32 * 8;
    const uint4 sv = *(const uint4*)(S + (size_t)row * 256 + c8);
    float x[8];
    x[0] = bflo(sv.x); x[1] = bfhi(sv.x);
    x[2] = bflo(sv.y); x[3] = bfhi(sv.y);
    x[4] = bflo(sv.z); x[5] = bfhi(sv.z);
    x[6] = bflo(sv.w); x[7] = bfhi(sv.w);
    float p = 0.f, q = 0.f;
    #pragma unroll
    for (int i = 0; i < 8; ++i) { p += x[i]; q += x[i] * x[i]; }
    #pragma unroll
    for (int o = 1; o < 32; o <<= 1) {
        p += __shfl_xor(p, o, 64);
        q += __shfl_xor(q, o, 64);
    }
    const float mean = p * (1.0f / 256.0f);
    const float var  = q * (1.0f / 256.0f) - mean * mean;
    const float rs   = rsqrtf(var + 1e-5f);
    const float4 gv0 = *(const float4*)(g + c8);
    const float4 gv1 = *(const float4*)(g + c8 + 4);
    const float4 bv0 = *(const float4*)(beta + c8);
    const float4 bv1 = *(const float4*)(beta + c8 + 4);
    const float gg[8] = {gv0.x, gv0.y, gv0.z, gv0.w, gv1.x, gv1.y, gv1.z, gv1.w};
    const float bb[8] = {bv0.x, bv0.y, bv0.z, bv0.w, bv1.x, bv1.y, bv1.z, bv1.w};
    float y[8];
    #pragma unroll
    for (int i = 0; i < 8; ++i)
        y[i] = (x[i] - mean) * rs * gg[i] + bb[i];
    if (HASF) {
        float4 o0; o0.x = y[0]; o0.y = y[1]; o0.z = y[2]; o0.w = y[3];
        float4 o1; o1.x = y[4]; o1.y = y[5]; o1.z = y[6]; o1.w = y[7];
        *(float4*)(outF + (size_t)row * 256 + c8) = o0;
        *(float4*)(outF + (size_t)row * 256 + c8 + 4) = o1;
    }
    if (HASB) {
        uint4 o2;
        o2.x = (unsigned)f2bf(y[0]) | ((unsigned)f2bf(y[1]) << 16);
        o2.y = (unsigned)f2bf(y[2]) | ((unsigned)f2bf(y[3]) << 16);
        o2.z = (unsigned)f2bf(y[4]) | ((unsigned)f2bf(y[5]) << 16);
        o2.w = (unsigned)f2bf(y[6]) | ((unsigned)f2bf(y[7]) << 16);
        *(uint4*)(outB + (size_t)row * 256 + c8) = o2;
    }
}

// ---------------------------------------------------------------------------
// fp32 [M,256] -> bf16 [M_PAD,256] with zero padding rows (layer 0 only)
// ---------------------------------------------------------------------------
__global__ __launch_bounds__(256)
void convpad(const float* __restrict__ X, unsigned short* __restrict__ Y, int M)
{
    const int idx = blockIdx.x * 256 + threadIdx.x;
    const int row = idx >> 6;
    const int c4  = (idx & 63) << 2;
    if (row >= M_PAD) return;
    float4 v = {0.f, 0.f, 0.f, 0.f};
    if (row < M) v = ((const float4*)(X + (size_t)row * 256))[c4 >> 2];
    unsigned p0 = (unsigned)f2bf(v.x) | ((unsigned)f2bf(v.y) << 16);
    unsigned p1 = (unsigned)f2bf(v.z) | ((unsigned)f2bf(v.w) << 16);
    uint2 o; o.x = p0; o.y = p1;
    *(uint2*)(Y + (size_t)row * 256 + c4) = o;
}

// ---------------------------------------------------------------------------
// Merged weight transpose+convert (12 segments, one dispatch).
// ---------------------------------------------------------------------------
struct WJobs {
    const float* W[12];
    unsigned short* WT[12];
    int K[12], N[12], tx[12], start[12];
};

__global__ __launch_bounds__(256)
void wtrans_all(WJobs jb)
{
    __shared__ float t[32][33];
    const int bx = blockIdx.x;
    int seg = 0;
    #pragma unroll
    for (int s = 1; s < 12; ++s) if (bx >= jb.start[s]) seg = s;
    const float* W = jb.W[seg];
    unsigned short* WT = jb.WT[seg];
    const int K = jb.K[seg], N = jb.N[seg], tx = jb.tx[seg];
    const int local = bx - jb.start[seg];
    const int n0 = (local % tx) * 32, k0 = (local / tx) * 32;
    const int c = threadIdx.x & 31, r0 = threadIdx.x >> 5;
    #pragma unroll
    for (int rr = r0; rr < 32; rr += 8)
        t[rr][c] = W[(size_t)(k0 + rr) * N + n0 + c];
    __syncthreads();
    #pragma unroll
    for (int rr = r0; rr < 32; rr += 8)
        WT[(size_t)(n0 + rr) * K + k0 + c] = f2bf(t[c][rr]);
}

// ---------------------------------------------------------------------------
// MSDA, 2-phase. XCD-swizzled block id (grid padded to 3328 = 8*416 so
// same-XCD blocks cover contiguous query ranges under round-robin dispatch).
// Phase B: raw-reinterpret hi-bf16 unpack (no AND), packed float2 fma.
// ---------------------------------------------------------------------------
__global__ __launch_bounds__(256)
void msda_kernel(const unsigned short* __restrict__ valb,
                 const unsigned short* __restrict__ oab,   // [M,384] bf16
                 const float* __restrict__ vr,
                 unsigned short* __restrict__ out)
{
    __shared__ __align__(16) char smeta[8 * 128 * 32];
    const int t = threadIdx.x;
    // XCD swizzle: consecutive blocks round-robin across 8 XCDs; remap so
    // blocks sharing an XCD handle adjacent queries (value-gather L2 reuse).
    const int bid = (blockIdx.x & 7) * 416 + (blockIdx.x >> 3);

    {
        const int wv = t >> 6, lane = t & 63;
        const int lqA = wv * 2 + (lane >> 5);
        const int bq = bid * 8 + lqA;
        const int h = (lane >> 2) & 7;
        const int j = lane & 3;
        if (bq < M_TOT) {
            const int b = (bq >= S_TOT) ? 1 : 0;
            const int q = bq - b * S_TOT;
            const int bofs = b * (S_TOT * 512);
            int Hq, rr, cc, lq;
            if (q < 10000)      { lq = 0; Hq = 100; rr = q / 100;              cc = q - rr * 100; }
            else if (q < 12500) { lq = 1; Hq = 50;  int r2 = q - 10000; rr = r2 / 50; cc = r2 - rr * 50; }
            else if (q < 13125) { lq = 2; Hq = 25;  int r2 = q - 12500; rr = r2 / 25; cc = r2 - rr * 25; }
            else                { lq = 3; Hq = 13;  int r2 = q - 13125; rr = r2 / 13; cc = r2 - rr * 13; }
            const float rxb = (cc + 0.5f) / (vr[(b * 4 + lq) * 2 + 0] * (float)Hq);
            const float ryb = (rr + 0.5f) / (vr[(b * 4 + lq) * 2 + 1] * (float)Hq);
            const int HWt[4] = {100, 50, 25, 13};
            const int stt[4] = {0, 10000, 12500, 13125};
            const int HW = HWt[j], st = stt[j];
            const float fW = (float)HW;
            const float refxw = rxb * vr[(b * 4 + j) * 2 + 0] * fW - 0.5f;
            const float refyw = ryb * vr[(b * 4 + j) * 2 + 1] * fW - 0.5f;
            const unsigned short* row = oab + (size_t)bq * 384;
            const uint2 lgu = *(const uint2*)(row + 256 + h * 16 + j * 4);
            const float l0 = bflo(lgu.x), l1 = bfhi(lgu.x);
            const float l2 = bflo(lgu.y), l3 = bfhi(lgu.y);
            float mx = fmaxf(fmaxf(l0, l1), fmaxf(l2, l3));
            mx = fmaxf(mx, __shfl_xor(mx, 1, 64));
            mx = fmaxf(mx, __shfl_xor(mx, 2, 64));
            const float e0 = __expf(l0 - mx), e1 = __expf(l1 - mx);
            const float e2 = __expf(l2 - mx), e3 = __expf(l3 - mx);
            float ss = e0 + e1 + e2 + e3;
            ss += __shfl_xor(ss, 1, 64);
            ss += __shfl_xor(ss, 2, 64);
            const float inv = 1.0f / ss;
            const uint4 ou = *(const uint4*)(row + h * 32 + j * 8);
            const float oxs[4] = {bflo(ou.x), bflo(ou.y), bflo(ou.z), bflo(ou.w)};
            const float oys[4] = {bfhi(ou.x), bfhi(ou.y), bfhi(ou.z), bfhi(ou.w)};
            const float aw[4]  = {e0 * inv, e1 * inv, e2 * inv, e3 * inv};
            char* mb = smeta + (size_t)(lqA * 128 + h * 16 + j * 4) * 32;
            const int swz = ((h * 4 + j) & 7) << 4;
            #pragma unroll
            for (int p = 0; p < 4; ++p) {
                const float x = refxw + oxs[p];
                const float y = refyw + oys[p];
                const float x0f = floorf(x), y0f = floorf(y);
                const int x0 = (int)x0f, y0 = (int)y0f;
                const float fx = x - x0f, fy = y - y0f;
                const float wb[4] = {(1.f - fx) * (1.f - fy), fx * (1.f - fy),
                                     (1.f - fx) * fy,         fx * fy};
                const int xs2[2] = {x0, x0 + 1};
                const int ys2[2] = {y0, y0 + 1};
                int iv[4]; float wv4[4];
                #pragma unroll
                for (int k = 0; k < 4; ++k) {
                    const int xi = xs2[k & 1], yi = ys2[k >> 1];
                    const bool vld = ((unsigned)xi < (unsigned)HW) && ((unsigned)yi < (unsigned)HW);
                    const int xc = min(max(xi, 0), HW - 1);
                    const int yc = min(max(yi, 0), HW - 1);
                    iv[k] = bofs + ((st + yc * HW + xc) << 9) + (h << 6);
                    wv4[k] = vld ? wb[k] * aw[p] : 0.0f;
                }
                int4 i4; i4.x = iv[0]; i4.y = iv[1]; i4.z = iv[2]; i4.w = iv[3];
                float4 w4; w4.x = wv4[0]; w4.y = wv4[1]; w4.z = wv4[2]; w4.w = wv4[3];
                *(int4*)(mb + ((p * 32) ^ swz)) = i4;
                *(float4*)(mb + ((p * 32 + 16) ^ swz)) = w4;
            }
        }
    }
    __syncthreads();
    {
        const int lq2 = t >> 5;
        const int r = t & 31;
        const int h2 = r >> 2;
        const int cg = r & 3;
        const int bq2 = bid * 8 + lq2;
        if (bq2 < M_TOT) {
            const char* vbase = (const char*)valb;
            const unsigned cgo = cg * 16;
            floatx2 a0 = {0.f, 0.f}, a1 = {0.f, 0.f}, a2 = {0.f, 0.f}, a3 = {0.f, 0.f};
            const char* mb2 = smeta + (size_t)(lq2 * 128 + h2 * 16) * 32;
            #pragma unroll 4
            for (int s = 0; s < 16; ++s) {
                const int swz2 = ((h2 * 4 + (s >> 2)) & 7) << 4;
                const int4  iv = *(const int4*)(mb2 + ((s * 32) ^ swz2));
                const float4 w4 = *(const float4*)(mb2 + ((s * 32 + 16) ^ swz2));
                const uint4 u0 = *(const uint4*)(vbase + (unsigned)(iv.x + cgo));
                const uint4 u1 = *(const uint4*)(vbase + (unsigned)(iv.y + cgo));
                const uint4 u2 = *(const uint4*)(vbase + (unsigned)(iv.z + cgo));
                const uint4 u3 = *(const uint4*)(vbase + (unsigned)(iv.w + cgo));
                // lo channel: exact (shift); hi channel: raw reinterpret —
                // low-half mantissa garbage is below bf16 rounding scale.
                #define ACC8(UU, WW) { \
                    const floatx2 w2 = {WW, WW}; \
                    const floatx2 t0 = {bflo(UU.x), braw(UU.x)}; \
                    const floatx2 t1 = {bflo(UU.y), braw(UU.y)}; \
                    const floatx2 t2 = {bflo(UU.z), braw(UU.z)}; \
                    const floatx2 t3 = {bflo(UU.w), braw(UU.w)}; \
                    a0 += w2 * t0; a1 += w2 * t1; a2 += w2 * t2; a3 += w2 * t3; }
                ACC8(u0, w4.x) ACC8(u1, w4.y) ACC8(u2, w4.z) ACC8(u3, w4.w)
                #undef ACC8
            }
            uint4 o;
            o.x = (unsigned)f2bf(a0.x) | ((unsigned)f2bf(a0.y) << 16);
            o.y = (unsigned)f2bf(a1.x) | ((unsigned)f2bf(a1.y) << 16);
            o.z = (unsigned)f2bf(a2.x) | ((unsigned)f2bf(a2.y) << 16);
            o.w = (unsigned)f2bf(a3.x) | ((unsigned)f2bf(a3.y) << 16);
            *(uint4*)(out + (size_t)bq2 * 256 + h2 * 32 + cg * 8) = o;
        }
    }
}

// ---------------------------------------------------------------------------
// Host-side orchestration
// ---------------------------------------------------------------------------
extern "C" void kernel_launch(void* const* d_in, const int* in_sizes, int n_in,
                              void* d_out, int out_size, void* d_ws, size_t ws_size,
                              hipStream_t stream)
{
    const float* src    = (const float*)d_in[0];
    const float* vr     = (const float*)d_in[2];
    const float* W_off  = (const float*)d_in[3];
    const float* b_off  = (const float*)d_in[4];
    const float* W_attn = (const float*)d_in[5];
    const float* b_attn = (const float*)d_in[6];
    const float* W_val  = (const float*)d_in[7];
    const float* b_val  = (const float*)d_in[8];
    const float* W_out  = (const float*)d_in[9];
    const float* b_out  = (const float*)d_in[10];
    const float* ln1_g  = (const float*)d_in[11];
    const float* ln1_b  = (const float*)d_in[12];
    const float* W1     = (const float*)d_in[13];
    const float* b1     = (const float*)d_in[14];
    const float* W2     = (const float*)d_in[15];
    const float* b2     = (const float*)d_in[16];
    const float* ln2_g  = (const float*)d_in[17];
    const float* ln2_b  = (const float*)d_in[18];
    float* out = (float*)d_out;

    const int M = M_TOT;

    // --- workspace (bytes), total 112,066,560 ---
    // [0,          54,525,952)  overlays:
    //     OAB  bf16 [M_PAD,384] at [0, 20,447,232)
    //     VALB bf16 [M_PAD,256] at [20,447,232, 34,078,720)
    //     S1   bf16 [M_PAD,256] at [0, 13,631,488)  (out-proj sum;
    //         lives after msda consumed OAB)
    // [54,525,952, 68,157,440)  X1B bf16 [M_PAD,256]  (post-LN1, bf16)
    // [68,157,440, 81,788,928)  S2  bf16 [M_PAD,256]  (FFN sum)
    // [81,788,928, 95,420,416)  RB  bf16 [M_PAD,256]  (x input, bf16)
    // [95,420,416,109,051,904)  YBF bf16 [M_PAD,256]  (msda out)
    // [109,051,904,112,066,560) WT  transposed weights
    char* wsb = (char*)d_ws;
    unsigned short* OAB  = (unsigned short*)wsb;
    unsigned short* VALB = (unsigned short*)(wsb + 20447232);
    unsigned short* S1   = (unsigned short*)wsb;
    unsigned short* X1B  = (unsigned short*)(wsb + 54525952);
    unsigned short* S2   = (unsigned short*)(wsb + 68157440);
    unsigned short* RB   = (unsigned short*)(wsb + 81788928);
    unsigned short* YBF  = (unsigned short*)(wsb + 95420416);
    unsigned short* WT   = (unsigned short*)(wsb + 109051904);

    const size_t LWT = 753664;
    const size_t oProj = 0, oOut = 163840, oW1 = 229376, oW2 = 491520;

    WJobs jb;
    int startAcc = 0;
    for (int i = 0; i < 2; ++i) {
        unsigned short* wt = WT + i * LWT;
        const float* srcs[6] = {W_val + i * 65536, W_off + i * 65536, W_attn + i * 32768,
                                W_out + i * 65536, W1 + i * 262144, W2 + i * 262144};
        unsigned short* dsts[6] = {wt + oProj, wt + oProj + 65536, wt + oProj + 131072,
                                   wt + oOut, wt + oW1, wt + oW2};
        const int Ks[6] = {256, 256, 256, 256, 256, 1024};
        const int Ns[6] = {256, 256, 128, 256, 1024, 256};
        for (int s = 0; s < 6; ++s) {
            const int idx = i * 6 + s;
            jb.W[idx] = srcs[s]; jb.WT[idx] = dsts[s];
            jb.K[idx] = Ks[s]; jb.N[idx] = Ns[s]; jb.tx[idx] = Ns[s] / 32;
            jb.start[idx] = startAcc;
            startAcc += (Ns[s] / 32) * (Ks[s] / 32);
        }
    }
    wtrans_all<<<dim3(startAcc), 256, 0, stream>>>(jb);

    const int GM64  = M_PAD / 64;       // 416
    const int GLN   = (M_TOT + 7) / 8;  // 3324
    const dim3 blk(256);

    for (int i = 0; i < 2; ++i) {
        unsigned short* wt = WT + i * LWT;

        if (i == 0)
            convpad<<<dim3(M_PAD / 4), blk, 0, stream>>>(src, RB, M);

        // merged projections: N=640 -> VALB (bf16) + OAB (bf16)
        // grid 5*416 blocks 1-D, nbmPer = 416/8 = 52
        mgemm<64, false, false, true, false><<<dim3(5 * GM64), blk, 0, stream>>>(
            RB, wt + oProj, b_val + i * 256, b_off + i * 256, b_attn + i * 128,
            nullptr, VALB, OAB, GM64 / 8, M, 640, 256);

        // deformable sampling (grid padded to 8*416 for the XCD swizzle)
        msda_kernel<<<dim3(3328), blk, 0, stream>>>(VALB, OAB, vr, YBF);

        // out-proj GEMM + bias + residual(RB) -> S1 bf16 (832 blocks)
        mgemm<64, false, false, false, true><<<dim3(2 * GM64), blk, 0, stream>>>(
            YBF, wt + oOut, b_out + i * 256, nullptr, nullptr,
            RB, S1, nullptr, GM64 / 8, M, 256, 256);

        // LN1: normalize S1 -> X1B bf16 (streaming, half-wave/row)
        ln_kernel<false, true><<<dim3(GLN), blk, 0, stream>>>(
            S1, ln1_g + i * 256, ln1_b + i * 256, nullptr, X1B, M);

        // fused FFN: S2 = relu(X1B@W1+b1)@W2 + b2 + X1B (416 blocks)
        ffn_fused<<<dim3(GM64), blk, 0, stream>>>(
            X1B, wt + oW1, b1 + i * 1024, wt + oW2, b2 + i * 256,
            S2, GM64 / 8);

        // LN2: normalize S2:
        //   layer 0 -> RB (bf16, next layer's x); layer 1 -> out (f32)
        if (i == 0)
            ln_kernel<false, true><<<dim3(GLN), blk, 0, stream>>>(
                S2, ln2_g + i * 256, ln2_b + i * 256, nullptr, RB, M);
        else
            ln_kernel<true, false><<<dim3(GLN), blk, 0, stream>>>(
                S2, ln2_g + i * 256, ln2_b + i * 256, out, nullptr, M);
    }
}